// Round 4
// baseline (547.560 us; speedup 1.0000x reference)
//
#include <hip/hip_runtime.h>

#define NN 32768
#define KK 16
#define DD 6
// State row per node-slot j: 256 B = h fp16[64] (natural) | c fp16[64] PERMUTED
// [lr][nt] (pos = (col&15)*4 + (col>>4)).  Row 0 = zero.
// Round-4 structure:
//  * k0/WxF ELIMINATED: Wx = (E[labels] @ W_w + W_b) is recomputed inside kd
//    via MFMA (matrix pipe was 3% busy; WxF cost 100 MB of HBM streaming).
//  * child ids preloaded (two int4: 32 B contiguous per lane) and the 8-child
//    gather loop is a hand-unrolled 2-deep pipeline (A/B reg sets, static
//    indices) so chunk loads get 2 compute-bodies of latency cover.
//  * WRITE_SIZE proven unreliable on gfx950 (R3: dense full-line stores left
//    it at 121 MB); steering by dur_us + FETCH_SIZE only.

typedef short short8 __attribute__((ext_vector_type(8)));
typedef float floatx4 __attribute__((ext_vector_type(4)));
typedef _Float16 half4v __attribute__((ext_vector_type(4)));
typedef _Float16 half8 __attribute__((ext_vector_type(8)));

__device__ __forceinline__ float sigm(float x) { return 1.0f / (1.0f + __expf(-x)); }
__device__ __forceinline__ float ftanh(float x) {
    float e = __expf(2.0f * x);
    return 1.0f - 2.0f / (e + 1.0f);
}
__device__ __forceinline__ unsigned short f2bf(float x) {   // RNE fp32->bf16
    union { float f; unsigned u; } v; v.f = x;
    unsigned r = v.u + 0x7FFF + ((v.u >> 16) & 1);
    return (unsigned short)(r >> 16);
}
__device__ __forceinline__ float bf2f(unsigned short h) {
    union { unsigned u; float f; } v; v.u = ((unsigned)h) << 16; return v.f;
}

// ---------------------------------------------------------------------------
// K_PREP: build global B-fragments once.  32768 values total, 1 per thread.
//   WwF: 16 nt x 2 ks x 64 ln x 8  bf16   (W_w,  256 cols)
//   BiF: 12 nt x 2 ks x 64 ln x 8  bf16   (U_iuo, 192 cols)
//   BfF:  4 nt x 2 ks x 64 ln x 8  fp16   (U_f,    64 cols)
__global__ __launch_bounds__(256) void k_prep(
    const float* __restrict__ W_w, const float* __restrict__ U_iuo,
    const float* __restrict__ U_f,
    unsigned short* __restrict__ WwF, unsigned short* __restrict__ BiF,
    _Float16* __restrict__ BfF)
{
    const int t = blockIdx.x * 256 + threadIdx.x;      // 0..32767
    if (t < 16384) {
        const int u = t, j = u & 7, ln = (u >> 3) & 63, ks = (u >> 9) & 1, nt = u >> 10;
        const int col = nt * 16 + (ln & 15), k = ks * 32 + (ln >> 4) * 8 + j;
        WwF[u] = f2bf(W_w[k * 256 + col]);
    } else if (t < 28672) {
        const int u = t - 16384, j = u & 7, ln = (u >> 3) & 63, ks = (u >> 9) & 1, nt = u >> 10;
        const int col = nt * 16 + (ln & 15), k = ks * 32 + (ln >> 4) * 8 + j;
        BiF[u] = f2bf(U_iuo[k * 192 + col]);
    } else {
        const int u = t - 28672, j = u & 7, ln = (u >> 3) & 63, ks = (u >> 9) & 1, nt = u >> 10;
        const int col = nt * 16 + (ln & 15), k = ks * 32 + (ln >> 4) * 8 + j;
        BfF[u] = (_Float16)U_f[k * 64 + col];
    }
}

// ---------------------------------------------------------------------------
// KD (fused): block = 32 nodes, 4 waves.  wave wv: group g=wv&1 (16 nodes),
// k-half kh=wv>>1 (children kh*8..+8).  Stage stride 272 B per row.
__global__ __launch_bounds__(256, 3) void kd_fused(
    const int* __restrict__ cidx, const int* __restrict__ labels,
    const float* __restrict__ E, const _Float16* __restrict__ sprev,
    const unsigned short* __restrict__ WwF, const float* __restrict__ W_b,
    const unsigned short* __restrict__ BiF, const _Float16* __restrict__ BfF,
    _Float16* __restrict__ snext, float* __restrict__ out, int first, int last)
{
    __shared__ __align__(16) _Float16 BfL[4096];             // [4 nt][2 ks][64 ln][8]
    __shared__ __align__(16) unsigned char stage[4 * 4352];  // per wave: 16 rows x 272 B
    const int tid = threadIdx.x;
    {   // stage U_f frags: 512 half8, 2 per thread
        const half8* __restrict__ src = (const half8*)BfF;
        half8* dst = (half8*)BfL;
        dst[tid] = src[tid];
        dst[tid + 256] = src[tid + 256];
    }
    const int ln = tid & 63, wv = tid >> 6;
    const int g = wv & 1, kh = wv >> 1;
    const int lr = ln & 15, qd = ln >> 4;
    const int n0 = blockIdx.x * 32;
    unsigned char* const myst = stage + wv * 4352;

    // ---- E A-frag + Wx f-tiles (each wave computes its group's copy)
    const int lab = labels[n0 + g * 16 + lr];
    const float4* __restrict__ e4 = (const float4*)(E + (size_t)lab * 64);
    short8 af[2];
#pragma unroll
    for (int ks = 0; ks < 2; ++ks) {
        const float4 v0 = e4[ks * 8 + qd * 2 + 0];
        const float4 v1 = e4[ks * 8 + qd * 2 + 1];
        short8 a;
        a[0] = (short)f2bf(v0.x); a[1] = (short)f2bf(v0.y);
        a[2] = (short)f2bf(v0.z); a[3] = (short)f2bf(v0.w);
        a[4] = (short)f2bf(v1.x); a[5] = (short)f2bf(v1.y);
        a[6] = (short)f2bf(v1.z); a[7] = (short)f2bf(v1.w);
        af[ks] = a;
    }
    const short8* __restrict__ bw = (const short8*)WwF;
    float wfx[4][4];                                   // f-gate Wx, C-layout, fp32
#pragma unroll
    for (int nt = 0; nt < 4; ++nt) {
        floatx4 a = (floatx4){0.f, 0.f, 0.f, 0.f};
        a = __builtin_amdgcn_mfma_f32_16x16x32_bf16(af[0], bw[(nt * 2 + 0) * 64 + ln], a, 0, 0, 0);
        a = __builtin_amdgcn_mfma_f32_16x16x32_bf16(af[1], bw[(nt * 2 + 1) * 64 + ln], a, 0, 0, 0);
        const float bb = W_b[nt * 16 + lr];
#pragma unroll
        for (int r = 0; r < 4; ++r) wfx[r][nt] = a[r] + bb;
    }
    __syncthreads();                                   // BfL ready

    float hsA[2][8];
    float bfv[4][4];
#pragma unroll
    for (int ks = 0; ks < 2; ++ks)
#pragma unroll
        for (int j = 0; j < 8; ++j) hsA[ks][j] = 0.f;
#pragma unroll
    for (int r = 0; r < 4; ++r)
#pragma unroll
        for (int nt = 0; nt < 4; ++nt) bfv[r][nt] = 0.f;

    if (!first) {
        const int m = ln >> 2, ch = ln & 3;            // gather: lane -> row m, chunk ch
        const size_t ib = (size_t)(n0 + g * 16 + m) * KK + kh * 8;
        const uint4* __restrict__ sp4 = (const uint4*)sprev;
        uint4* const st4 = (uint4*)myst;
        const half8* __restrict__ bl = (const half8*)BfL;
        const int4 idv0 = *(const int4*)&cidx[ib];     // 8 ids, 32 B contiguous
        const int4 idv1 = *(const int4*)&cidx[ib + 4];
        uint4 A0, A1, A2, A3, B0, B1, B2, B3;

#define GLOAD(R0, R1, R2, R3, idv) {                                   \
        const size_t b_ = (size_t)(idv) * 16 + ch;                     \
        R0 = sp4[b_]; R1 = sp4[b_ + 4]; R2 = sp4[b_ + 8]; R3 = sp4[b_ + 12]; }
#define SWRITE(R0, R1, R2, R3) {                                       \
        st4[m * 17 + ch] = R0;      st4[m * 17 + ch + 4] = R1;         \
        st4[m * 17 + ch + 8] = R2;  st4[m * 17 + ch + 12] = R3; }
#define BODY() {                                                       \
        const half8 hf0 = *(const half8*)(myst + lr * 272 + qd * 16);  \
        const half8 hf1 = *(const half8*)(myst + lr * 272 + 64 + qd * 16); \
        half4v cq[4];                                                  \
        _Pragma("unroll") for (int r = 0; r < 4; ++r)                  \
            cq[r] = *(const half4v*)(myst + (qd * 4 + r) * 272 + 128 + lr * 8); \
        _Pragma("unroll") for (int nt = 0; nt < 4; ++nt) {             \
            floatx4 gg = (floatx4){0.f, 0.f, 0.f, 0.f};                \
            gg = __builtin_amdgcn_mfma_f32_16x16x32_f16(hf0, bl[(nt * 2 + 0) * 64 + ln], gg, 0, 0, 0); \
            gg = __builtin_amdgcn_mfma_f32_16x16x32_f16(hf1, bl[(nt * 2 + 1) * 64 + ln], gg, 0, 0, 0); \
            _Pragma("unroll") for (int r = 0; r < 4; ++r)              \
                bfv[r][nt] = fmaf(sigm(wfx[r][nt] + gg[r]), (float)cq[r][nt], bfv[r][nt]); \
        }                                                              \
        _Pragma("unroll") for (int j = 0; j < 8; ++j) {                \
            hsA[0][j] += (float)hf0[j]; hsA[1][j] += (float)hf1[j]; } }

        // 2-deep pipeline: each GLOAD has two BODYs of cover before its wait.
        GLOAD(A0, A1, A2, A3, idv0.x);
        GLOAD(B0, B1, B2, B3, idv0.y);
        SWRITE(A0, A1, A2, A3);
        GLOAD(A0, A1, A2, A3, idv0.z);
        BODY(); SWRITE(B0, B1, B2, B3); GLOAD(B0, B1, B2, B3, idv0.w);
        BODY(); SWRITE(A0, A1, A2, A3); GLOAD(A0, A1, A2, A3, idv1.x);
        BODY(); SWRITE(B0, B1, B2, B3); GLOAD(B0, B1, B2, B3, idv1.y);
        BODY(); SWRITE(A0, A1, A2, A3); GLOAD(A0, A1, A2, A3, idv1.z);
        BODY(); SWRITE(B0, B1, B2, B3); GLOAD(B0, B1, B2, B3, idv1.w);
        BODY(); SWRITE(A0, A1, A2, A3);
        BODY(); SWRITE(B0, B1, B2, B3);
        BODY();
#undef GLOAD
#undef SWRITE
#undef BODY

        // ---- combine k-halves across wave pairs (reuse stage memory)
        __syncthreads();
        float* const pbh = (float*)(stage + g * 4352);
        float* const pbb = (float*)(stage + (2 + g) * 4352);
        if (kh == 1) {
#pragma unroll
            for (int ks = 0; ks < 2; ++ks)
#pragma unroll
                for (int j = 0; j < 8; ++j) pbh[ln * 17 + ks * 8 + j] = hsA[ks][j];
#pragma unroll
            for (int r = 0; r < 4; ++r)
#pragma unroll
                for (int nt = 0; nt < 4; ++nt) pbb[ln * 17 + r * 4 + nt] = bfv[r][nt];
        }
        __syncthreads();
        if (kh == 0) {
#pragma unroll
            for (int ks = 0; ks < 2; ++ks)
#pragma unroll
                for (int j = 0; j < 8; ++j) hsA[ks][j] += pbh[ln * 17 + ks * 8 + j];
#pragma unroll
            for (int r = 0; r < 4; ++r)
#pragma unroll
                for (int nt = 0; nt < 4; ++nt) bfv[r][nt] += pbb[ln * 17 + r * 4 + nt];
        }
    }
    if (kh == 0) {
        // ---- iuo GEMM: in-register split-bf16 hsum @ U_iuo, 12 out-tiles
        floatx4 acc[12];
#pragma unroll
        for (int nt = 0; nt < 12; ++nt) acc[nt] = (floatx4){0.f, 0.f, 0.f, 0.f};
        if (!first) {
            short8 ahi[2], alo[2];
#pragma unroll
            for (int ks = 0; ks < 2; ++ks)
#pragma unroll
                for (int j = 0; j < 8; ++j) {
                    const float v = hsA[ks][j];
                    const unsigned short hi = f2bf(v);
                    ahi[ks][j] = (short)hi;
                    alo[ks][j] = (short)f2bf(v - bf2f(hi));
                }
            const short8* __restrict__ bi = (const short8*)BiF;
#pragma unroll
            for (int nt = 0; nt < 12; ++nt) {
                floatx4 a = (floatx4){0.f, 0.f, 0.f, 0.f};
#pragma unroll
                for (int ks = 0; ks < 2; ++ks) {
                    const short8 bu = bi[(nt * 2 + ks) * 64 + ln];
                    a = __builtin_amdgcn_mfma_f32_16x16x32_bf16(alo[ks], bu, a, 0, 0, 0);
                    a = __builtin_amdgcn_mfma_f32_16x16x32_bf16(ahi[ks], bu, a, 0, 0, 0);
                }
                acc[nt] = a;
            }
        }
        // ---- gate epilogue: Wx i/u/o tiles via MFMA (fp32, no fp16 round-trip);
        //      row images assembled in wave-private LDS, full-line copies out.
        _Float16* const rb = (_Float16*)myst;          // [16 rows][128 halves]
#pragma unroll
        for (int nt = 0; nt < 4; ++nt) {
            floatx4 wi = (floatx4){0.f, 0.f, 0.f, 0.f};
            floatx4 wu = (floatx4){0.f, 0.f, 0.f, 0.f};
            floatx4 wo = (floatx4){0.f, 0.f, 0.f, 0.f};
            wi = __builtin_amdgcn_mfma_f32_16x16x32_bf16(af[0], bw[((4 + nt) * 2 + 0) * 64 + ln], wi, 0, 0, 0);
            wi = __builtin_amdgcn_mfma_f32_16x16x32_bf16(af[1], bw[((4 + nt) * 2 + 1) * 64 + ln], wi, 0, 0, 0);
            wu = __builtin_amdgcn_mfma_f32_16x16x32_bf16(af[0], bw[((8 + nt) * 2 + 0) * 64 + ln], wu, 0, 0, 0);
            wu = __builtin_amdgcn_mfma_f32_16x16x32_bf16(af[1], bw[((8 + nt) * 2 + 1) * 64 + ln], wu, 0, 0, 0);
            wo = __builtin_amdgcn_mfma_f32_16x16x32_bf16(af[0], bw[((12 + nt) * 2 + 0) * 64 + ln], wo, 0, 0, 0);
            wo = __builtin_amdgcn_mfma_f32_16x16x32_bf16(af[1], bw[((12 + nt) * 2 + 1) * 64 + ln], wo, 0, 0, 0);
            const float bi_ = W_b[(4 + nt) * 16 + lr];
            const float bu_ = W_b[(8 + nt) * 16 + lr];
            const float bo_ = W_b[(12 + nt) * 16 + lr];
#pragma unroll
            for (int r = 0; r < 4; ++r) {
                const int mrow = qd * 4 + r;
                const float ig = sigm(acc[nt][r] + wi[r] + bi_);
                const float ug = ftanh(acc[4 + nt][r] + wu[r] + bu_);
                const float og = sigm(acc[8 + nt][r] + wo[r] + bo_);
                const float nc = fmaf(ig, ug, bfv[r][nt]);
                const float nh = og * ftanh(nc);
                if (last) {
                    out[(size_t)(n0 + g * 16 + mrow) * 64 + nt * 16 + lr] = nh;
                } else {
                    rb[mrow * 128 + nt * 16 + lr] = (_Float16)nh;       // h natural
                    rb[mrow * 128 + 64 + lr * 4 + nt] = (_Float16)nc;   // c permuted
                }
            }
        }
        if (!last) {
            // full-line copy: 16 rows x 256 B contiguous (rows n0+g*16+1 ..)
            const uint4* const s4 = (const uint4*)myst;
            uint4* const d4 = (uint4*)((char*)snext + (size_t)(n0 + g * 16 + 1) * 256);
#pragma unroll
            for (int i = 0; i < 4; ++i) d4[ln + i * 64] = s4[ln + i * 64];
        }
    }
    if (!last && blockIdx.x == 0 && tid < 64)
        ((unsigned*)snext)[tid] = 0u;                  // zero init-state row
}

extern "C" void kernel_launch(void* const* d_in, const int* in_sizes, int n_in,
                              void* d_out, int out_size, void* d_ws, size_t ws_size,
                              hipStream_t stream)
{
    const int*   labels = (const int*)d_in[0];    // [6, 32768]
    const int*   child  = (const int*)d_in[1];    // [6, 32768, 16]
    const float* E      = (const float*)d_in[2];  // [100000, 64]
    const float* W_w    = (const float*)d_in[3];  // [64, 256]
    const float* W_b    = (const float*)d_in[4];  // [256]
    const float* U_f    = (const float*)d_in[5];  // [64, 64]
    const float* U_iuo  = (const float*)d_in[6];  // [64, 192]
    float* out = (float*)d_out;

    // ws: s0,s1 = (NN+1)*256 B state ping-pong (8.4 MB each);
    //     then WwF/BiF/BfF frag tables (64 KB).  WxF eliminated.
    _Float16* s0 = (_Float16*)d_ws;
    _Float16* s1 = s0 + (size_t)(NN + 1) * 128;
    unsigned short* WwF = (unsigned short*)(s1 + (size_t)(NN + 1) * 128);
    unsigned short* BiF = WwF + 16384;
    _Float16* BfF = (_Float16*)(BiF + 12288);

    k_prep<<<128, 256, 0, stream>>>(W_w, U_iuo, U_f, WwF, BiF, BfF);

    _Float16* sp = s0;
    _Float16* sn = s1;
    for (int d = 0; d < DD; ++d) {
        const int last = (d == DD - 1);
        kd_fused<<<NN / 32, 256, 0, stream>>>(
            child + (size_t)d * NN * KK, labels + (size_t)d * NN, E, sp,
            WwF, W_b, BiF, BfF, sn, out, d == 0, last);
        _Float16* ts = sp; sp = sn; sn = ts;
    }
}